// Round 5
// baseline (28449.652 us; speedup 1.0000x reference)
//
#include <hip/hip_runtime.h>
#include <stdint.h>

typedef unsigned long long u64t;

__device__ __forceinline__ float sigf(float x) { return 1.f / (1.f + __expf(-x)); }
__device__ __forceinline__ float tanhf_s(float x) {
    float ax = fabsf(x);
    float t = __expf(-2.f * ax);
    float r = (1.f - t) / (1.f + t);
    return copysignf(r, x);
}

// ---------------------------------------------------------------------------
// K1: char LSTM, register-weight version.
// 512 blocks x 256 thr, 16 words/block sequentially.
// ---------------------------------------------------------------------------
__global__ __launch_bounds__(256, 2) void k_char_lstm(
    const int* __restrict__ chars, const float* __restrict__ char_emb,
    const float* __restrict__ Wih, const float* __restrict__ Whh,
    const float* __restrict__ bih, const float* __restrict__ bhh,
    float* __restrict__ h_char, int words_per_block)
{
    __shared__ float X[768];    // 12 steps x 64
    __shared__ float gl[256];   // activated gates [g][e]
    __shared__ float hl[64];    // current h
    const int t = threadIdx.x;
    const int g = t >> 6, e = t & 63;

    float wih[64], whh[64];
    {
        const float4* p1 = (const float4*)(Wih + t * 64);
        const float4* p2 = (const float4*)(Whh + t * 64);
#pragma unroll
        for (int q = 0; q < 16; ++q) {
            float4 a = p1[q];
            wih[4*q+0] = a.x; wih[4*q+1] = a.y; wih[4*q+2] = a.z; wih[4*q+3] = a.w;
        }
#pragma unroll
        for (int q = 0; q < 16; ++q) {
            float4 b = p2[q];
            whh[4*q+0] = b.x; whh[4*q+1] = b.y; whh[4*q+2] = b.z; whh[4*q+3] = b.w;
        }
    }
    const float bias = bih[t] + bhh[t];

    for (int wi = 0; wi < words_per_block; ++wi) {
        const int w = blockIdx.x * words_per_block + wi;
        const int* crow = chars + w * 12;
        for (int q = t; q < 768; q += 256)
            X[q] = char_emb[crow[q >> 6] * 64 + (q & 63)];
        if (t < 64) hl[t] = 0.f;
        __syncthreads();

        float c = 0.f, hreg = 0.f;
        for (int st = 0; st < 12; ++st) {
            float s_ = bias;
            const float4* xv4 = (const float4*)(X + st * 64);
            const float4* hv4 = (const float4*)hl;
#pragma unroll
            for (int q = 0; q < 16; ++q) {
                float4 x4 = xv4[q];
                s_ += wih[4*q+0]*x4.x + wih[4*q+1]*x4.y + wih[4*q+2]*x4.z + wih[4*q+3]*x4.w;
            }
#pragma unroll
            for (int q = 0; q < 16; ++q) {
                float4 h4 = hv4[q];
                s_ += whh[4*q+0]*h4.x + whh[4*q+1]*h4.y + whh[4*q+2]*h4.z + whh[4*q+3]*h4.w;
            }
            gl[t] = (g == 2) ? tanhf_s(s_) : sigf(s_);
            __syncthreads();
            if (g == 0) {
                float ii = gl[e], ff = gl[64 + e], gg = gl[128 + e], oo = gl[192 + e];
                c = ff * c + ii * gg;
                hreg = oo * tanhf_s(c);
                hl[e] = hreg;
            }
            __syncthreads();
        }
        if (g == 0) h_char[w * 64 + e] = hreg;
    }
}

// ---------------------------------------------------------------------------
// K2: materialize X[w] = [word_emb[sent[w]] (256) | h_char[w] (64)]. f32.
// ---------------------------------------------------------------------------
__global__ __launch_bounds__(320) void k_build_x(
    const int* __restrict__ sentence, const float* __restrict__ word_emb,
    const float* __restrict__ h_char, float* __restrict__ X)
{
    const int w = blockIdx.x, t = threadIdx.x;
    float v;
    if (t < 256) v = word_emb[(size_t)sentence[w] * 256 + t];
    else         v = h_char[(size_t)w * 64 + (t - 256)];
    X[(size_t)w * 320 + t] = v;
}

// ---------------------------------------------------------------------------
// K3: pack W_out [64][512] -> WP[k4*256 + j*4 + c] = W_out[j][k4*4+c]
// ---------------------------------------------------------------------------
__global__ __launch_bounds__(256) void k_pack_wout(const float* __restrict__ W_out, float* __restrict__ WP)
{
    int i = blockIdx.x * 256 + threadIdx.x;  // < 32768
    int c = i & 3, j = (i >> 2) & 63, k4 = i >> 8;
    WP[i] = W_out[j * 512 + k4 * 4 + c];
}

// ---------------------------------------------------------------------------
// K4: persistent word LSTM, f32, latency-tuned.
// 64 WGs x 256 thr. Thread map: e=t>>5 (elem), g=(t>>3)&3 (gate), ks=t&7.
// Weights in true VGPRs (launch_bounds(256,1) -> no spill).
// Per step: prime 4-deep poll ring -> xdot (hidden) -> pipelined poll
// (sampling ~L/4) -> LDS stage h -> barrier -> hdot -> shfl-combine gates
// (no 2nd barrier, no serial section) -> all-lane redundant cell update ->
// lane (t&31)==0 publishes tagged u64.
// Double-buffered Hpub[2][512]; slot s&1 holds tag s. No-overtake proof:
// tag s+2 into a slot requires ALL WGs published s+1, which requires every
// wave of every WG to have passed its step-s hdot reads.
// Spin bound 1<<14: normal detect is <10 ring cycles; worst-case full-kernel
// timeout is seconds (fast wrong-answer, never a dead container).
// ---------------------------------------------------------------------------
#define PLOAD(p) __hip_atomic_load((p), __ATOMIC_RELAXED, __HIP_MEMORY_SCOPE_AGENT)

__global__ __launch_bounds__(256, 1) void k_word_lstm(
    const float* __restrict__ Whh, const float* __restrict__ Wih,
    const float* __restrict__ X,
    const float* __restrict__ bih, const float* __restrict__ bhh,
    u64t* Hpub, float* __restrict__ ys)
{
    __shared__ float h_lds[544];
    const int t = threadIdx.x, wg = blockIdx.x;
    const int e = t >> 5, g = (t >> 3) & 3, ks = t & 7;
    const int grow = g * 512 + wg * 8 + e;

    float whhr[64];
    {
        const float4* wsrc = (const float4*)(Whh + (size_t)grow * 512 + ks * 64);
#pragma unroll
        for (int j = 0; j < 16; ++j) {
            float4 v = wsrc[j];
            whhr[4*j] = v.x; whhr[4*j+1] = v.y; whhr[4*j+2] = v.z; whhr[4*j+3] = v.w;
        }
    }
    float wihr[40];
    {
        const float4* wsrc = (const float4*)(Wih + (size_t)grow * 320 + ks * 40);
#pragma unroll
        for (int j = 0; j < 10; ++j) {
            float4 v = wsrc[j];
            wihr[4*j] = v.x; wihr[4*j+1] = v.y; wihr[4*j+2] = v.z; wihr[4*j+3] = v.w;
        }
    }
    const float bias = bih[grow] + bhh[grow];

    const int lidx1 = t + ((t >> 6) << 2);
    const int lidx2 = (t + 256) + (((t + 256) >> 6) << 2);
    const float* hb = h_lds + ks * 68;
    const bool pub = ((t & 31) == 0);
    float c = 0.f;

    for (int s = 0; s < 8192; ++s) {
        const unsigned wantu = (unsigned)s;
        u64t* slot = Hpub + ((s & 1) << 9);
        u64t* sl1 = slot + t;
        u64t* sl2 = slot + t + 256;

        // prime 4-deep snapshot ring (8 independent in-flight loads)
        u64t q10 = PLOAD(sl1), q20 = PLOAD(sl2);
        u64t q11 = PLOAD(sl1), q21 = PLOAD(sl2);
        u64t q12 = PLOAD(sl1), q22 = PLOAD(sl2);
        u64t q13 = PLOAD(sl1), q23 = PLOAD(sl2);

        // xdot: independent of h_{s-1}; hides under ring latency
        float x0 = 0.f, x1 = 0.f, x2 = 0.f, x3 = 0.f;
        {
            const float4* xr = (const float4*)(X + (size_t)s * 320 + ks * 40);
#pragma unroll
            for (int q = 0; q < 10; ++q) {
                float4 xv = xr[q];
                x0 += wihr[4*q]   * xv.x;
                x1 += wihr[4*q+1] * xv.y;
                x2 += wihr[4*q+2] * xv.z;
                x3 += wihr[4*q+3] * xv.w;
            }
        }

        // pipelined poll: check oldest snapshot, reissue; ~L/4 sample spacing
        bool d1 = false, d2 = false;
        unsigned p1 = 0, p2 = 0;
#define POLL_PHASE(S1, S2) \
        if (!d1) { if ((unsigned)((S1) >> 32) == wantu) { d1 = true; p1 = (unsigned)(S1); } else (S1) = PLOAD(sl1); } \
        if (!d2) { if ((unsigned)((S2) >> 32) == wantu) { d2 = true; p2 = (unsigned)(S2); } else (S2) = PLOAD(sl2); } \
        if (d1 && d2) break;
        for (int spin = 0; spin < (1 << 14); ++spin) {
            POLL_PHASE(q10, q20)
            POLL_PHASE(q11, q21)
            POLL_PHASE(q12, q22)
            POLL_PHASE(q13, q23)
        }
#undef POLL_PHASE

        h_lds[lidx1] = __uint_as_float(p1);
        h_lds[lidx2] = __uint_as_float(p2);
        __syncthreads();

        // hdot over h[ks*64 .. +64)
        float s0 = x0, s1 = x1, s2 = x2, s3 = x3;
#pragma unroll
        for (int q = 0; q < 16; ++q) {
            float4 hv = *(const float4*)(hb + 4 * q);
            s0 += whhr[4*q]   * hv.x;
            s1 += whhr[4*q+1] * hv.y;
            s2 += whhr[4*q+2] * hv.z;
            s3 += whhr[4*q+3] * hv.w;
        }
        float sum = (s0 + s1) + (s2 + s3);
        sum += __shfl_xor(sum, 1);
        sum += __shfl_xor(sum, 2);
        sum += __shfl_xor(sum, 4);
        sum += bias;                      // uniform across the ks-octet

        // activation: gate g (tanh for g==2, sigmoid else) via one exp
        float y  = (g == 2) ? sum : 0.5f * sum;
        float ax = fabsf(y);
        float ez = __expf(-2.f * ax);
        float th = copysignf((1.f - ez) / (1.f + ez), y);
        float act = (g == 2) ? th : 0.5f * th + 0.5f;

        // butterfly across gate subgroups: collect all 4 gates in-register
        float b8  = __shfl_xor(act, 8);   // gate g^1
        float b16 = __shfl_xor(act, 16);  // gate g^2
        float b24 = __shfl_xor(b8, 16);   // gate g^3
        float ii = (g == 0) ? act : (g == 1) ? b8  : (g == 2) ? b16 : b24;
        float ff = (g == 0) ? b8  : (g == 1) ? act : (g == 2) ? b24 : b16;
        float gg = (g == 0) ? b16 : (g == 1) ? b24 : (g == 2) ? act : b8;
        float oo = (g == 0) ? b24 : (g == 1) ? b16 : (g == 2) ? b8  : act;

        c = ff * c + ii * gg;             // identical in all 32 lanes of elem e
        float h = oo * tanhf_s(c);

        if (pub) {
            u64t pv = ((u64t)(s + 1) << 32) | (u64t)__float_as_uint(h);
            __hip_atomic_store(Hpub + (((s + 1) & 1) << 9) + wg * 8 + e, pv,
                               __ATOMIC_RELAXED, __HIP_MEMORY_SCOPE_AGENT);
            ys[(size_t)s * 512 + wg * 8 + e] = h;
        }
        // No 2nd barrier: h_lds can only be overwritten at step s+1 after the
        // poll sees tag s+1 on ALL slots, incl. this WG's — published by lanes
        // in every wave only after that wave's hdot reads completed.
    }
}
#undef PLOAD

// ---------------------------------------------------------------------------
// K5: logits = ys @ W_out.T + b_out, log_softmax per row. 4 rows/block.
// ---------------------------------------------------------------------------
__global__ __launch_bounds__(256) void k_proj(
    const float* __restrict__ ys, const float* __restrict__ WP,
    const float* __restrict__ b_out, float* __restrict__ out)
{
    __shared__ float yl[4 * 516];
    const int t = threadIdx.x;
    const size_t base = (size_t)blockIdx.x * 4 * 512;
#pragma unroll
    for (int i = 0; i < 8; ++i) {
        int q = t + 256 * i;
        yl[(q >> 9) * 516 + (q & 511)] = ys[base + q];
    }
    __syncthreads();
    const int row = t >> 6, j = t & 63;
    const float* yr = yl + row * 516;
    float acc = b_out[j];
    for (int k4 = 0; k4 < 128; ++k4) {
        float4 wv = *(const float4*)(WP + k4 * 256 + j * 4);
        float4 yv = *(const float4*)(yr + k4 * 4);
        acc += wv.x * yv.x + wv.y * yv.y + wv.z * yv.z + wv.w * yv.w;
    }
    float m = acc;
#pragma unroll
    for (int d = 1; d < 64; d <<= 1) m = fmaxf(m, __shfl_xor(m, d));
    float p = __expf(acc - m);
    float ssum = p;
#pragma unroll
    for (int d = 1; d < 64; d <<= 1) ssum += __shfl_xor(ssum, d);
    out[(size_t)blockIdx.x * 256 + t] = acc - m - __logf(ssum);
}

__global__ void k_signal(float* out, float v) { out[0] = v; }

// ---------------------------------------------------------------------------
extern "C" void kernel_launch(void* const* d_in, const int* in_sizes, int n_in,
                              void* d_out, int out_size, void* d_ws, size_t ws_size,
                              hipStream_t stream)
{
    const int*   char_sentence = (const int*)d_in[0];
    const int*   sentence      = (const int*)d_in[1];
    const float* char_emb      = (const float*)d_in[2];
    const float* word_emb      = (const float*)d_in[3];
    const float* Wih_c         = (const float*)d_in[4];
    const float* Whh_c         = (const float*)d_in[5];
    const float* bih_c         = (const float*)d_in[6];
    const float* bhh_c         = (const float*)d_in[7];
    const float* Wih_w         = (const float*)d_in[8];
    const float* Whh_w         = (const float*)d_in[9];
    const float* bih_w         = (const float*)d_in[10];
    const float* bhh_w         = (const float*)d_in[11];
    const float* W_out         = (const float*)d_in[12];
    const float* b_out         = (const float*)d_in[13];
    float* out = (float*)d_out;
    char* ws = (char*)d_ws;

    // ws layout (all f32)
    float* X      = (float*)(ws);                        // 8192*320*4 = 10,485,760
    float* ys     = (float*)(ws + 10485760);             // 8192*512*4 = 16,777,216
    float* h_char = (float*)(ws + 27262976);             // 8192*64*4  =  2,097,152
    u64t*  Hpub   = (u64t*)(ws + 29360128);              // 2*512*8    =      8,192
    float* WP     = (float*)(ws + 29368320);             // 64*512*4   =    131,072
    const size_t need = 29368320 + 131072;
    if (ws_size < need) {
        k_signal<<<1, 1, 0, stream>>>(out, (float)(ws_size >> 20));
        return;
    }

    k_char_lstm<<<512, 256, 0, stream>>>(char_sentence, char_emb, Wih_c, Whh_c, bih_c, bhh_c, h_char, 16);
    k_build_x<<<8192, 320, 0, stream>>>(sentence, word_emb, h_char, X);
    k_pack_wout<<<128, 256, 0, stream>>>(W_out, WP);
    hipMemsetAsync(Hpub, 0, 8192, stream);  // reset both tag buffers every launch
    k_word_lstm<<<64, 256, 0, stream>>>(Whh_w, Wih_w, X, bih_w, bhh_w, Hpub, ys);
    k_proj<<<2048, 256, 0, stream>>>(ys, WP, b_out, out);
}

// Round 6
// 16859.050 us; speedup vs baseline: 1.6875x; 1.6875x over previous
//
#include <hip/hip_runtime.h>
#include <stdint.h>

typedef unsigned long long u64t;

__device__ __forceinline__ float sigf(float x) { return 1.f / (1.f + __expf(-x)); }
__device__ __forceinline__ float tanhf_s(float x) {
    float ax = fabsf(x);
    float t = __expf(-2.f * ax);
    float r = (1.f - t) / (1.f + t);
    return copysignf(r, x);
}

// ---------------------------------------------------------------------------
// K1: char LSTM, register-weight version. 512 blocks x 256 thr, 16 words each.
// ---------------------------------------------------------------------------
__global__ __launch_bounds__(256, 2) void k_char_lstm(
    const int* __restrict__ chars, const float* __restrict__ char_emb,
    const float* __restrict__ Wih, const float* __restrict__ Whh,
    const float* __restrict__ bih, const float* __restrict__ bhh,
    float* __restrict__ h_char, int words_per_block)
{
    __shared__ float X[768];    // 12 steps x 64
    __shared__ float gl[256];   // activated gates [g][e]
    __shared__ float hl[64];    // current h
    const int t = threadIdx.x;
    const int g = t >> 6, e = t & 63;

    float wih[64], whh[64];
    {
        const float4* p1 = (const float4*)(Wih + t * 64);
        const float4* p2 = (const float4*)(Whh + t * 64);
#pragma unroll
        for (int q = 0; q < 16; ++q) {
            float4 a = p1[q];
            wih[4*q+0] = a.x; wih[4*q+1] = a.y; wih[4*q+2] = a.z; wih[4*q+3] = a.w;
        }
#pragma unroll
        for (int q = 0; q < 16; ++q) {
            float4 b = p2[q];
            whh[4*q+0] = b.x; whh[4*q+1] = b.y; whh[4*q+2] = b.z; whh[4*q+3] = b.w;
        }
    }
    const float bias = bih[t] + bhh[t];

    for (int wi = 0; wi < words_per_block; ++wi) {
        const int w = blockIdx.x * words_per_block + wi;
        const int* crow = chars + w * 12;
        for (int q = t; q < 768; q += 256)
            X[q] = char_emb[crow[q >> 6] * 64 + (q & 63)];
        if (t < 64) hl[t] = 0.f;
        __syncthreads();

        float c = 0.f, hreg = 0.f;
        for (int st = 0; st < 12; ++st) {
            float s_ = bias;
            const float4* xv4 = (const float4*)(X + st * 64);
            const float4* hv4 = (const float4*)hl;
#pragma unroll
            for (int q = 0; q < 16; ++q) {
                float4 x4 = xv4[q];
                s_ += wih[4*q+0]*x4.x + wih[4*q+1]*x4.y + wih[4*q+2]*x4.z + wih[4*q+3]*x4.w;
            }
#pragma unroll
            for (int q = 0; q < 16; ++q) {
                float4 h4 = hv4[q];
                s_ += whh[4*q+0]*h4.x + whh[4*q+1]*h4.y + whh[4*q+2]*h4.z + whh[4*q+3]*h4.w;
            }
            gl[t] = (g == 2) ? tanhf_s(s_) : sigf(s_);
            __syncthreads();
            if (g == 0) {
                float ii = gl[e], ff = gl[64 + e], gg = gl[128 + e], oo = gl[192 + e];
                c = ff * c + ii * gg;
                hreg = oo * tanhf_s(c);
                hl[e] = hreg;
            }
            __syncthreads();
        }
        if (g == 0) h_char[w * 64 + e] = hreg;
    }
}

// ---------------------------------------------------------------------------
// K2: X[w] = [word_emb[sent[w]] (256) | h_char[w] (64)]. f32.
// ---------------------------------------------------------------------------
__global__ __launch_bounds__(320) void k_build_x(
    const int* __restrict__ sentence, const float* __restrict__ word_emb,
    const float* __restrict__ h_char, float* __restrict__ X)
{
    const int w = blockIdx.x, t = threadIdx.x;
    float v;
    if (t < 256) v = word_emb[(size_t)sentence[w] * 256 + t];
    else         v = h_char[(size_t)w * 64 + (t - 256)];
    X[(size_t)w * 320 + t] = v;
}

// ---------------------------------------------------------------------------
// K3: pack W_out [64][512] -> WP[k4*256 + j*4 + c] = W_out[j][k4*4+c]
// ---------------------------------------------------------------------------
__global__ __launch_bounds__(256) void k_pack_wout(const float* __restrict__ W_out, float* __restrict__ WP)
{
    int i = blockIdx.x * 256 + threadIdx.x;  // < 32768
    int c = i & 3, j = (i >> 2) & 63, k4 = i >> 8;
    WP[i] = W_out[j * 512 + k4 * 4 + c];
}

// ---------------------------------------------------------------------------
// K4: persistent word LSTM, f32. 64 WGs x 512 thr.
// Map: e=t>>6 (elem, = wave id), g=(t>>4)&3 (gate), ks=t&15 (k-slice).
// Per-thread weights: Whh[grow][ks*32..+32) (32f) + Wih[grow][ks*20..+20)
// (20f) = 52 floats -> true VGPRs at ANY allocator setting (no reload).
// Per step: X row load + xdot (early, off critical path) -> poll own slot
// (1 relaxed agent atomic in flight) -> stage h to LDS -> syncthreads_or
// (barrier + uniform abort) -> hdot (32 MAC) -> shfl_xor(1,2,4,8) row
// reduce -> activation (1 exp) -> gate butterfly shfl_xor(16,32) -> all-lane
// cell update -> lane0/wave publishes tagged u64 -> barrier2 (closes h_lds
// overwrite race). ys buffered in LDS, dumped every 64 steps.
// Hpub double-buffered [2][512]; slot s&1 carries tag s. Publish of tag s+2
// into a buffer requires ALL WGs consumed tag s from it (barrier1 orders
// each WG's polls before its publish) -> no overtaking.
// Global spin budget ~4M: normal use ~2 polls/step; worst-case abort ~1s,
// uniform across the block via syncthreads_or.
// ---------------------------------------------------------------------------
#define PLOAD(p) __hip_atomic_load((p), __ATOMIC_RELAXED, __HIP_MEMORY_SCOPE_AGENT)

__global__ __launch_bounds__(512, 1) void k_word_lstm(
    const float* __restrict__ Whh, const float* __restrict__ Wih,
    const float* __restrict__ X,
    const float* __restrict__ bih, const float* __restrict__ bhh,
    u64t* Hpub, float* __restrict__ ys)
{
    __shared__ float h_lds[576];      // h[k] at k + (k>>5)*4  (2-way banks max)
    __shared__ float ys_buf[64][8];
    const int t = threadIdx.x, wg = blockIdx.x;
    const int e = t >> 6, g = (t >> 4) & 3, ks = t & 15;
    const int grow = g * 512 + wg * 8 + e;

    float whhr[32];
    {
        const float4* ws_ = (const float4*)(Whh + (size_t)grow * 512 + ks * 32);
#pragma unroll
        for (int j = 0; j < 8; ++j) {
            float4 v = ws_[j];
            whhr[4*j] = v.x; whhr[4*j+1] = v.y; whhr[4*j+2] = v.z; whhr[4*j+3] = v.w;
        }
    }
    float wihr[20];
    {
        const float4* ws_ = (const float4*)(Wih + (size_t)grow * 320 + ks * 20);
#pragma unroll
        for (int j = 0; j < 5; ++j) {
            float4 v = ws_[j];
            wihr[4*j] = v.x; wihr[4*j+1] = v.y; wihr[4*j+2] = v.z; wihr[4*j+3] = v.w;
        }
    }
    const float bias = bih[grow] + bhh[grow];

    const int sidx = t + ((t >> 5) << 2);    // LDS index for staged h[t]
    const float* hb = h_lds + ks * 36;       // 32 floats + 4 pad per slice
    float c = 0.f;
    int bud = 1 << 22;

    for (int s = 0; s < 8192; ++s) {
        // ---- xdot first: independent of h_{s-1}, runs while producers work
        float x0 = 0.f, x1 = 0.f, x2 = 0.f, x3 = 0.f;
        {
            const float4* xr = (const float4*)(X + (size_t)s * 320 + ks * 20);
#pragma unroll
            for (int q = 0; q < 5; ++q) {
                float4 xv = xr[q];
                x0 += wihr[4*q]   * xv.x;
                x1 += wihr[4*q+1] * xv.y;
                x2 += wihr[4*q+2] * xv.z;
                x3 += wihr[4*q+3] * xv.w;
            }
        }

        // ---- poll own slot (single outstanding load)
        const unsigned want = (unsigned)s;
        u64t* sl = Hpub + ((s & 1) << 9) + t;
        u64t v;
        do { v = PLOAD(sl); } while ((unsigned)(v >> 32) != want && --bud > 0);
        h_lds[sidx] = __uint_as_float((unsigned)v);

        // ---- barrier1 + uniform abort (never desyncs the block)
        if (__syncthreads_or(bud <= 0)) break;

        // ---- hdot over h[ks*32 .. +32)
        float s0 = x0, s1 = x1, s2 = x2, s3 = x3;
#pragma unroll
        for (int q = 0; q < 8; ++q) {
            float4 hv = *(const float4*)(hb + 4 * q);
            s0 += whhr[4*q]   * hv.x;
            s1 += whhr[4*q+1] * hv.y;
            s2 += whhr[4*q+2] * hv.z;
            s3 += whhr[4*q+3] * hv.w;
        }
        float sum = (s0 + s1) + (s2 + s3);
        sum += __shfl_xor(sum, 1);
        sum += __shfl_xor(sum, 2);
        sum += __shfl_xor(sum, 4);
        sum += __shfl_xor(sum, 8);
        sum += bias;                          // row sum, all 16 ks-lanes

        // activation: tanh for g==2, sigmoid else (one exp)
        float y  = (g == 2) ? sum : 0.5f * sum;
        float ax = fabsf(y);
        float ez = __expf(-2.f * ax);
        float th = copysignf((1.f - ez) / (1.f + ez), y);
        float act = (g == 2) ? th : 0.5f * th + 0.5f;

        // gate butterfly: bits 4,5 of lane = g
        float b16 = __shfl_xor(act, 16);      // gate g^1
        float b32 = __shfl_xor(act, 32);      // gate g^2
        float b48 = __shfl_xor(b16, 32);      // gate g^3
        float ii = (g == 0) ? act : (g == 1) ? b16 : (g == 2) ? b32 : b48;
        float ff = (g == 0) ? b16 : (g == 1) ? act : (g == 2) ? b48 : b32;
        float gg = (g == 0) ? b32 : (g == 1) ? b48 : (g == 2) ? act : b16;
        float oo = (g == 0) ? b48 : (g == 1) ? b32 : (g == 2) ? b16 : act;

        c = ff * c + ii * gg;                 // identical across wave e
        float h = oo * tanhf_s(c);

        if ((t & 63) == 0) {                  // lane 0 of wave e
            u64t pv = ((u64t)(s + 1) << 32) | (u64t)__float_as_uint(h);
            __hip_atomic_store(Hpub + (((s + 1) & 1) << 9) + wg * 8 + e, pv,
                               __ATOMIC_RELAXED, __HIP_MEMORY_SCOPE_AGENT);
            ys_buf[s & 63][e] = h;            // LDS, keeps vmcnt path clean
        }
        __syncthreads();                      // barrier2: hdot reads done before
                                              // next staging; ys_buf visible
        if ((s & 63) == 63) {
            int row = t >> 3, col = t & 7;    // dump 64x8 block, coalesced-ish
            ys[(size_t)(s - 63 + row) * 512 + wg * 8 + col] = ys_buf[row][col];
            // safe vs next-step publishers: they write ys_buf only after
            // barrier1(s+1), which all dump readers must pass first.
        }
    }
}
#undef PLOAD

// ---------------------------------------------------------------------------
// K5: logits = ys @ W_out.T + b_out, log_softmax per row. 4 rows/block.
// ---------------------------------------------------------------------------
__global__ __launch_bounds__(256) void k_proj(
    const float* __restrict__ ys, const float* __restrict__ WP,
    const float* __restrict__ b_out, float* __restrict__ out)
{
    __shared__ float yl[4 * 516];
    const int t = threadIdx.x;
    const size_t base = (size_t)blockIdx.x * 4 * 512;
#pragma unroll
    for (int i = 0; i < 8; ++i) {
        int q = t + 256 * i;
        yl[(q >> 9) * 516 + (q & 511)] = ys[base + q];
    }
    __syncthreads();
    const int row = t >> 6, j = t & 63;
    const float* yr = yl + row * 516;
    float acc = b_out[j];
    for (int k4 = 0; k4 < 128; ++k4) {
        float4 wv = *(const float4*)(WP + k4 * 256 + j * 4);
        float4 yv = *(const float4*)(yr + k4 * 4);
        acc += wv.x * yv.x + wv.y * yv.y + wv.z * yv.z + wv.w * yv.w;
    }
    float m = acc;
#pragma unroll
    for (int d = 1; d < 64; d <<= 1) m = fmaxf(m, __shfl_xor(m, d));
    float p = __expf(acc - m);
    float ssum = p;
#pragma unroll
    for (int d = 1; d < 64; d <<= 1) ssum += __shfl_xor(ssum, d);
    out[(size_t)blockIdx.x * 256 + t] = acc - m - __logf(ssum);
}

__global__ void k_signal(float* out, float v) { out[0] = v; }

// ---------------------------------------------------------------------------
extern "C" void kernel_launch(void* const* d_in, const int* in_sizes, int n_in,
                              void* d_out, int out_size, void* d_ws, size_t ws_size,
                              hipStream_t stream)
{
    const int*   char_sentence = (const int*)d_in[0];
    const int*   sentence      = (const int*)d_in[1];
    const float* char_emb      = (const float*)d_in[2];
    const float* word_emb      = (const float*)d_in[3];
    const float* Wih_c         = (const float*)d_in[4];
    const float* Whh_c         = (const float*)d_in[5];
    const float* bih_c         = (const float*)d_in[6];
    const float* bhh_c         = (const float*)d_in[7];
    const float* Wih_w         = (const float*)d_in[8];
    const float* Whh_w         = (const float*)d_in[9];
    const float* bih_w         = (const float*)d_in[10];
    const float* bhh_w         = (const float*)d_in[11];
    const float* W_out         = (const float*)d_in[12];
    const float* b_out         = (const float*)d_in[13];
    float* out = (float*)d_out;
    char* ws = (char*)d_ws;

    // ws layout (all f32)
    float* X      = (float*)(ws);                        // 8192*320*4 = 10,485,760
    float* ys     = (float*)(ws + 10485760);             // 8192*512*4 = 16,777,216
    float* h_char = (float*)(ws + 27262976);             // 8192*64*4  =  2,097,152
    u64t*  Hpub   = (u64t*)(ws + 29360128);              // 2*512*8    =      8,192
    float* WP     = (float*)(ws + 29368320);             // 64*512*4   =    131,072
    const size_t need = 29368320 + 131072;
    if (ws_size < need) {
        k_signal<<<1, 1, 0, stream>>>(out, (float)(ws_size >> 20));
        return;
    }

    k_char_lstm<<<512, 256, 0, stream>>>(char_sentence, char_emb, Wih_c, Whh_c, bih_c, bhh_c, h_char, 16);
    k_build_x<<<8192, 320, 0, stream>>>(sentence, word_emb, h_char, X);
    k_pack_wout<<<128, 256, 0, stream>>>(W_out, WP);
    hipMemsetAsync(Hpub, 0, 8192, stream);  // reset both tag buffers every launch
    k_word_lstm<<<64, 512, 0, stream>>>(Whh_w, Wih_w, X, bih_w, bhh_w, Hpub, ys);
    k_proj<<<2048, 256, 0, stream>>>(ys, WP, b_out, out);
}